// Round 12
// baseline (218.890 us; speedup 1.0000x reference)
//
#include <hip/hip_runtime.h>
#include <hip/hip_bf16.h>
#include <stdint.h>

// ---------------------------------------------------------------------------
// CustomConvLayer: out[b,o,h,w] = sum_{c,dh,dw} xpad[b,c,h+dh,w+dw] * W[o,c,dh*3+dw]
// Implicit-im2col GEMM, bf16 MFMA 16x16x32. M=B*H*W, N=128, K=576.
//
// R15: R10 + float4 transpose loads (96 -> 24 VMEM instr/thread). Model from
// R10-R14: per-block critical path ~10.7us with little cross-block overlap;
// largest serial chunk = transpose prologue's 96 scalar loads (~12 exposed
// L2/L3 round-trips at the compiler's ~8-deep in-flight window). float4
// loads keep perfect coalescing (lane stride 16B -> 512B segments) and cut
// latency rounds 4x. Write side: thread now produces 4 chunks at stride-4 v,
// which under cq^(v&7) would 16-way bank-conflict -> slab swizzle changed to
// cq^((v>>2)&7) at ALL sites (edge zeros, staging writes, aF reads). Reads
// stay conflict-free (16 lanes -> 16 distinct bank starts); writes <=4-way.
// K-loop (reg bF), epilogue, xform_w: byte-identical to R10.
// ---------------------------------------------------------------------------

typedef __bf16 bf16x8 __attribute__((ext_vector_type(8)));
typedef float  f32x4  __attribute__((ext_vector_type(4)));

// ---------------- weights -> fragment-order BtF[s][quad][n] 16B chunks -------
// chunk(s,quad,n)[r] = W[n][c][tap] with k = s*32+quad*8+r, tap=k>>6, c=k&63
__global__ __launch_bounds__(256) void xform_w(const float* __restrict__ wgt,
                                               __bf16* __restrict__ BtF) {
  const int t = blockIdx.x * 256 + threadIdx.x;  // chunk id
  if (t >= 9216) return;
  const int s = t >> 9, rem = t & 511, quad = rem >> 7, n = rem & 127;
  bf16x8 o;
#pragma unroll
  for (int r = 0; r < 8; ++r) {
    const int k = s * 32 + quad * 8 + r;
    const int tap = k >> 6, c = k & 63;
    o[r] = (__bf16)wgt[(n * 64 + c) * 9 + tap];
  }
  *(bf16x8*)(BtF + (size_t)t * 8) = o;
}

// slab chunk slot for (v, cq): swizzle on (v>>2)&7 (write pattern is stride-4 v)
#define SLOT(v, cq) (((v) << 3) + ((cq) ^ (((v) >> 2) & 7)))

// ---------------- fused conv: block=(b,h); float4 in-register transpose ------
__global__ __launch_bounds__(256) void conv_mfma(const float* __restrict__ x,
                                                 const __bf16* __restrict__ BtF,
                                                 float* __restrict__ out) {
  __shared__ alignas(16) __bf16 Aslab[3120 * 8];  // 49,920 B: 3 rows x 130 wp x 64 c
  const int tid  = threadIdx.x;
  const int lane = tid & 63;
  const int wave = tid >> 6;
  const int quad = lane >> 4;
  const int l16  = lane & 15;
  // XCD-aware swizzle: same-XCD blocks get contiguous (b,h) -> x-row L2 reuse
  const int rank = (blockIdx.x & 7) * 256 + (blockIdx.x >> 3);
  const int b = rank >> 7;
  const int h = rank & 127;
  const int wm = wave >> 1;  // M half
  const int wn = wave & 1;   // N half

  // ---- edge chunks wp=0 / wp=129 -> zeros (48 chunks; ordered by the barrier)
  if (tid < 48) {
    const int r3 = tid >> 4, wp = ((tid >> 3) & 1) * 129, cq = tid & 7;
    const int v = r3 * 130 + wp;
    const bf16x8 z = {};
    *(bf16x8*)(Aslab + (size_t)SLOT(v, cq) * 8) = z;
  }

  // ---- transpose staging: thread (c8 = tid>>5, wl = tid&31) owns w-quad
  // 4wl..4wl+3 of one c-octet. Per slab row: 8 float4 loads (lanes stride
  // 16B -> 512B contiguous segments), cvt in reg, 4 swizzled 16B ds_writes.
  // 24 VMEM instructions total (was 96 scalar).
  const int c8 = tid >> 5;
  const int wl = tid & 31;
  const float* xb = x + ((size_t)b * 64 + c8 * 8) * 16384 + 4 * wl;  // + cc*16384 + xr*128

  f32x4 g[3][8];  // all rows' payloads; constant-indexed under full unroll

#pragma unroll
  for (int r = 0; r < 3; ++r) {
    const int xr = h - 1 + r;
    if (xr >= 0 && xr <= 127) {
      const float* p0 = xb + (size_t)xr * 128;
#pragma unroll
      for (int cc = 0; cc < 8; ++cc) g[r][cc] = *(const f32x4*)(p0 + (size_t)cc * 16384);
    }
  }
#pragma unroll
  for (int r = 0; r < 3; ++r) {
    const int xr = h - 1 + r;
#pragma unroll
    for (int j = 0; j < 4; ++j) {
      bf16x8 pk = {};
      if (xr >= 0 && xr <= 127) {
#pragma unroll
        for (int cc = 0; cc < 8; ++cc) pk[cc] = (__bf16)g[r][cc][j];
      }
      const int v = r * 130 + 1 + 4 * wl + j;
      *(bf16x8*)(Aslab + (size_t)SLOT(v, c8) * 8) = pk;
    }
  }
  __syncthreads();  // the only barrier

  // ---- R10-verbatim compute (new SLOT swizzle): 18 s-steps, no barriers ----
  f32x4 acc[4][4] = {};
#pragma unroll
  for (int s = 0; s < 18; ++s) {
    const int tap = s >> 1;
    const int dh = tap / 3, dw = tap % 3;
    const int cq = ((s & 1) << 2) + quad;  // 16B chunk index within a 64-elem row
    bf16x8 aF[4], bF[4];                   // plain locals, constant-indexed (SROA)
#pragma unroll
    for (int i = 0; i < 4; ++i) {
      const int m = (wm << 6) + (i << 4) + l16;
      const int v = dh * 130 + m + dw;
      aF[i] = *(const bf16x8*)(Aslab + (size_t)SLOT(v, cq) * 8);
      const int n = (wn << 6) + (i << 4) + l16;
      bF[i] = *(const bf16x8*)(BtF + ((size_t)((s * 4 + quad) * 128 + n) << 3));
    }
#pragma unroll
    for (int i = 0; i < 4; ++i)
#pragma unroll
      for (int j = 0; j < 4; ++j)
        acc[i][j] = __builtin_amdgcn_mfma_f32_16x16x32_bf16(aF[i], bF[j], acc[i][j], 0, 0, 0);
  }

  // epilogue: D col = lane&15 = n, row = quad*4+reg = m (out w). Plain stores.
#pragma unroll
  for (int j = 0; j < 4; ++j) {
    const int n = (wn << 6) + (j << 4) + l16;
    float* orow = out + (((size_t)(b * 128 + n) * 128 + h) << 7);
#pragma unroll
    for (int i = 0; i < 4; ++i) {
      const int m0 = (wm << 6) + (i << 4) + (quad << 2);
      *(f32x4*)(orow + m0) = acc[i][j];  // quads 0..3 tile one 64B line per n
    }
  }
}

// ---------------- fallback (if workspace too small): direct fp32 conv -------
__global__ void conv_naive(const float* __restrict__ x, const float* __restrict__ wgt,
                           float* __restrict__ out, int total) {
  int idx = blockIdx.x * 256 + threadIdx.x;
  if (idx >= total) return;
  const int w = idx & 127;
  const int h = (idx >> 7) & 127;
  const int o = (idx >> 14) & 127;
  const int b = idx >> 21;
  float s = 0.f;
  for (int c = 0; c < 64; ++c) {
    const float* xc = x + ((size_t)(b * 64 + c) * 128) * 128;
    const float* wc = wgt + (o * 64 + c) * 9;
    for (int dh = 0; dh < 3; ++dh) {
      const int hh = h + dh - 1;
      if (hh < 0 || hh >= 128) continue;
      for (int dw = 0; dw < 3; ++dw) {
        const int ww = w + dw - 1;
        if (ww < 0 || ww >= 128) continue;
        s += xc[hh * 128 + ww] * wc[dh * 3 + dw];
      }
    }
  }
  out[idx] = s;
}

extern "C" void kernel_launch(void* const* d_in, const int* in_sizes, int n_in,
                              void* d_out, int out_size, void* d_ws, size_t ws_size,
                              hipStream_t stream) {
  const float* x   = (const float*)d_in[0];
  const float* wgt = (const float*)d_in[1];
  float* out = (float*)d_out;

  const size_t BTF_BYTES = 9216ull * 16;  // 147456 (L2-resident)

  if (ws_size < BTF_BYTES) {
    const int total = 16 * 128 * 128 * 128;
    conv_naive<<<(total + 255) / 256, 256, 0, stream>>>(x, wgt, out, total);
    return;
  }

  __bf16* BtF = (__bf16*)d_ws;

  xform_w<<<36, 256, 0, stream>>>(wgt, BtF);
  conv_mfma<<<2048, 256, 0, stream>>>(x, BtF, out);
}